// Round 17
// baseline (219.137 us; speedup 1.0000x reference)
//
#include <hip/hip_runtime.h>
#include <math.h>

#define EPSF 1e-8f

typedef _Float16 f16x8 __attribute__((ext_vector_type(8)));
typedef float f32x4 __attribute__((ext_vector_type(4)));

#define GLOAD_LDS16(g, l)                                                      \
  __builtin_amdgcn_global_load_lds(                                            \
      (const __attribute__((address_space(1))) unsigned int*)(g),              \
      (__attribute__((address_space(3))) unsigned int*)(l), 16, 0, 0)

#define WAITV(n) asm volatile("s_waitcnt vmcnt(" #n ")" ::: "memory")
#define BAR() __builtin_amdgcn_s_barrier()

__device__ __forceinline__ unsigned int ord_from_float(float f) {
  unsigned int u = __float_as_uint(f);
  return (u & 0x80000000u) ? ~u : (u | 0x80000000u);
}

__device__ __forceinline__ float float_from_ord(unsigned int o) {
  return (o & 0x80000000u) ? __uint_as_float(o & 0x7fffffffu)
                           : __uint_as_float(~o);
}

__device__ __forceinline__ unsigned long long shfl_xor_u64(unsigned long long x, int m) {
  int lo = __shfl_xor((int)(unsigned int)(x & 0xffffffffull), m, 64);
  int hi = __shfl_xor((int)(unsigned int)(x >> 32), m, 64);
  return ((unsigned long long)(unsigned int)hi << 32) | (unsigned int)lo;
}

// ---------------- merged prep kernel (vectorized, r9 padded layout) ----------------
// Segments padded to DP (=192), KPA = 3*DP = 576 (1152-B rows, 128B-aligned —
// r16 showed the unpadded 1088-B stride costs ~8% in the GEMM):
//   Acat row: [hi(log) @0 | hi(log) @DP | lo(log) @2DP], zeros in [D,DP) each
//   Bcat row: [hi(tgt) @0 | lo(tgt) @DP | hi(tgt) @2DP]
// Also: s_in (row sums), s_st (Stirling sums), packed init.
__global__ __launch_bounds__(64) void prep_kernel(
    const float* __restrict__ inp, const float* __restrict__ tgt,
    _Float16* __restrict__ Acat, _Float16* __restrict__ Bcat,
    float* __restrict__ s_in, float* __restrict__ s_st,
    unsigned long long* __restrict__ packed,
    int N, int M, int Npad, int Mpad, int D, int DP) {
  const int r = blockIdx.x;
  const int tid = threadIdx.x;
  const int KPA = 3 * DP;
  const int NC4 = D >> 2;  // exact float4 chunks (D=180 -> 45)
  float sa = 0.f, sb = 0.f;

  _Float16* const arow = (r < Npad) ? Acat + (size_t)r * KPA : nullptr;
  _Float16* const brow = (r < Mpad) ? Bcat + (size_t)r * KPA : nullptr;
  const float4* const ain = (const float4*)(inp + (size_t)r * D);
  const float4* const bin = (const float4*)(tgt + (size_t)r * D);

  for (int c = tid; c < NC4; c += 64) {
    if (arow) {
      float4 v = (r < N) ? ain[c] : make_float4(0.f, 0.f, 0.f, 0.f);
      float xs[4] = {v.x, v.y, v.z, v.w};
      #pragma unroll
      for (int e = 0; e < 4; ++e) {
        float x = xs[e];
        sa += x;
        float lg = (r < N) ? logf(x + EPSF) : 0.f;
        _Float16 h = (_Float16)lg;
        _Float16 l = (_Float16)(lg - (float)h);
        int d = c * 4 + e;
        arow[d] = h;
        arow[DP + d] = h;
        arow[2 * DP + d] = l;
      }
    }
    if (brow) {
      float4 v = (r < M) ? bin[c] : make_float4(0.f, 0.f, 0.f, 0.f);
      float xs[4] = {v.x, v.y, v.z, v.w};
      #pragma unroll
      for (int e = 0; e < 4; ++e) {
        float x = xs[e];
        if (x > 1.0f)
          sb += x * logf(x) - x + 0.5f * logf(6.283185307179586f * x);
        _Float16 h = (_Float16)x;
        _Float16 l = (_Float16)(x - (float)h);
        int d = c * 4 + e;
        brow[d] = h;
        brow[DP + d] = l;
        brow[2 * DP + d] = h;
      }
    }
  }
  // scalar remainder of [NC4*4, D) (none for D=180)
  for (int d = (NC4 << 2) + tid; d < D; d += 64) {
    if (arow) {
      float x = (r < N) ? inp[(size_t)r * D + d] : 0.f;
      sa += x;
      float lg = (r < N) ? logf(x + EPSF) : 0.f;
      _Float16 h = (_Float16)lg;
      _Float16 l = (_Float16)(lg - (float)h);
      arow[d] = h; arow[DP + d] = h; arow[2 * DP + d] = l;
    }
    if (brow) {
      float x = (r < M) ? tgt[(size_t)r * D + d] : 0.f;
      if (x > 1.0f)
        sb += x * logf(x) - x + 0.5f * logf(6.283185307179586f * x);
      _Float16 h = (_Float16)x;
      _Float16 l = (_Float16)(x - (float)h);
      brow[d] = h; brow[DP + d] = l; brow[2 * DP + d] = h;
    }
  }
  // zero the per-segment pad [D, DP) x 3 segments (DP-D = 12 for D=180)
  for (int d = D + tid; d < DP; d += 64) {
    if (arow) { arow[d] = (_Float16)0.f; arow[DP + d] = (_Float16)0.f; arow[2 * DP + d] = (_Float16)0.f; }
    if (brow) { brow[d] = (_Float16)0.f; brow[DP + d] = (_Float16)0.f; brow[2 * DP + d] = (_Float16)0.f; }
  }

  #pragma unroll
  for (int m = 1; m < 64; m <<= 1) {
    sa += __shfl_xor(sa, m, 64);
    sb += __shfl_xor(sb, m, 64);
  }
  if (tid == 0) {
    if (r < N) { s_in[r] = sa; packed[r] = ~0ull; }
    if (r < M) s_st[r] = sb;
  }
}

// ---------------- MFMA pair-min kernel (r9 core — fastest verified) ----------------
// 256x256 tile, 8 waves (2Mx4N), BK=32, 2 LDS buffers (64 KiB dynamic).
// Per step: STAGE(t+1, other buf) -> COMPUTE(t) -> WAITV(0) -> BAR.
#define BT 256
#define UNITH 8192  // halves per (buf,op) unit: 256 rows x 32 halves = 16 KB

__global__ __launch_bounds__(512, 2) void mfma_pair_min_kernel(
    const _Float16* __restrict__ Acat, const _Float16* __restrict__ Bcat,
    const float* __restrict__ s_st, unsigned long long* __restrict__ packed,
    int N, int M, int KPA, int gx) {
  extern __shared__ __align__(16) _Float16 smem[];  // 4 * UNITH = 64 KiB
  const int t = threadIdx.x;
  const int lane = t & 63;
  const int wid = t >> 6;   // 0..7
  const int wr = wid >> 2;  // 0..1 -> 128 output rows
  const int wc = wid & 3;   // 0..3 -> 64 output cols

  // XCD chunking + column-major traversal inside each chunk (round-6 verified)
  const int nwg = gridDim.x;
  const int q8 = nwg >> 3;
  const int xcd = blockIdx.x & 7;
  const int i8 = blockIdx.x >> 3;
  int brow, bcol;
  if (q8 % gx == 0) {
    int bh = q8 / gx;
    brow = xcd * bh + i8 % bh;
    bcol = i8 / bh;
  } else {
    int wg = xcd * q8 + i8;
    brow = wg / gx;
    bcol = wg % gx;
  }
  const int row0 = brow * BT;
  const int col0 = bcol * BT;

  f32x4 acc[8][4] = {};

  // Staging (round-3/4 verified swizzle): LDS dest linear; global source slot
  // pre-swizzled: LDS(r,s) = global(r, s^((r>>1)&3)). 0 bank conflicts.
  const int srow = lane >> 2;
  const int gs = (lane & 3) ^ ((lane >> 3) & 3);
  const _Float16* a0 = Acat + (size_t)(row0 + wid * 32 + srow) * KPA + gs * 8;
  const _Float16* a1 = a0 + (size_t)16 * KPA;
  const _Float16* b0 = Bcat + (size_t)(col0 + wid * 32 + srow) * KPA + gs * 8;
  const _Float16* b1 = b0 + (size_t)16 * KPA;

#define STAGE(buf_)                                                            \
  do {                                                                         \
    _Float16* dA_ = smem + (buf_) * 2 * UNITH + wid * 1024;                    \
    _Float16* dB_ = dA_ + UNITH;                                               \
    GLOAD_LDS16(a0, dA_);                                                      \
    GLOAD_LDS16(a1, dA_ + 512);                                                \
    GLOAD_LDS16(b0, dB_);                                                      \
    GLOAD_LDS16(b1, dB_ + 512);                                                \
  } while (0)

#define ADV() do { a0 += 32; a1 += 32; b0 += 32; b1 += 32; } while (0)

  const int rl = lane & 15;
  const int qq = lane >> 4;
  const int sa = qq ^ ((rl >> 1) & 3);  // swizzled k-slot

#define COMPUTE(buf_)                                                          \
  do {                                                                         \
    const _Float16* pA_ = smem + (buf_) * 2 * UNITH;                           \
    const _Float16* pB_ = pA_ + UNITH;                                         \
    f16x8 af[8], bf[4];                                                        \
    _Pragma("unroll")                                                          \
    for (int m = 0; m < 8; ++m)                                                \
      af[m] = *(const f16x8*)(pA_ + (wr * 128 + m * 16 + rl) * 32 + sa * 8);   \
    _Pragma("unroll")                                                          \
    for (int n = 0; n < 4; ++n)                                                \
      bf[n] = *(const f16x8*)(pB_ + (wc * 64 + n * 16 + rl) * 32 + sa * 8);    \
    __builtin_amdgcn_s_setprio(1);                                             \
    _Pragma("unroll")                                                          \
    for (int m = 0; m < 8; ++m)                                                \
      _Pragma("unroll")                                                        \
      for (int n = 0; n < 4; ++n)                                              \
        acc[m][n] = __builtin_amdgcn_mfma_f32_16x16x32_f16(af[m], bf[n],       \
                                                           acc[m][n], 0, 0, 0); \
    __builtin_amdgcn_s_setprio(0);                                             \
  } while (0)

  const int NT = KPA >> 5;  // 18 for D=180 (KPA=576)

  STAGE(0);
  WAITV(0);
  BAR();
  for (int kt = 0; kt < NT - 1; ++kt) {
    ADV();
    STAGE((kt + 1) & 1);  // issue next-step loads first (MFMA covers latency)
    COMPUTE(kt & 1);
    WAITV(0);             // own 4 loads landed; BAR syncs all waves' stages
    BAR();
  }
  COMPUTE((NT - 1) & 1);

#undef STAGE
#undef ADV
#undef COMPUTE

  // ---- fused min/argmin epilogue (atomicMin, verified) ----
  // C/D frag: col = lane&15, row = (lane>>4)*4 + reg   [guide §3, m89-verified]
  float stv[4];
  #pragma unroll
  for (int n = 0; n < 4; ++n) {
    int gj = col0 + wc * 64 + n * 16 + rl;
    stv[n] = (gj < M) ? s_st[gj] : __builtin_inff();
  }
  #pragma unroll
  for (int m = 0; m < 8; ++m) {
    #pragma unroll
    for (int g = 0; g < 4; ++g) {
      int grow = row0 + wr * 128 + m * 16 + qq * 4 + g;
      unsigned long long bst = ~0ull;
      #pragma unroll
      for (int n = 0; n < 4; ++n) {
        int gj = col0 + wc * 64 + n * 16 + rl;
        float val = stv[n] - acc[m][n][g];
        unsigned long long p =
            ((unsigned long long)ord_from_float(val) << 32) | (unsigned int)gj;
        if (p < bst) bst = p;
      }
      #pragma unroll
      for (int mm = 1; mm < 16; mm <<= 1) {
        unsigned long long o = shfl_xor_u64(bst, mm);
        if (o < bst) bst = o;
      }
      if (rl == 0 && grow < N) atomicMin(&packed[grow], bst);
    }
  }
}

// ---------------- reduce + final ----------------
__global__ __launch_bounds__(256) void reduce_kernel(
    const unsigned long long* __restrict__ packed,
    const float* __restrict__ s_in, float* __restrict__ out,
    unsigned long long* __restrict__ sumbuf, int N) {
  int i = blockIdx.x * 256 + threadIdx.x;
  double local = 0.0;
  if (i < N) {
    unsigned long long p = packed[i];
    out[1 + i] = (float)(unsigned int)(p & 0xffffffffull);
    float val = float_from_ord((unsigned int)(p >> 32));
    local = (double)(s_in[i] + val);
  }
  __shared__ double sh[256];
  sh[threadIdx.x] = local;
  __syncthreads();
  for (int o = 128; o > 0; o >>= 1) {
    if (threadIdx.x < o) sh[threadIdx.x] += sh[threadIdx.x + o];
    __syncthreads();
  }
  if (threadIdx.x == 0) {
    long long q = __double2ll_rn(sh[0] * 1048576.0);  // fixed-point: deterministic
    atomicAdd(sumbuf, (unsigned long long)q);
  }
}

__global__ void final_kernel(const unsigned long long* __restrict__ sumbuf,
                             float* __restrict__ out, int N) {
  if (threadIdx.x == 0)
    out[0] = (float)(((double)(long long)sumbuf[0] / 1048576.0) / (double)N);
}

extern "C" void kernel_launch(void* const* d_in, const int* in_sizes, int n_in,
                              void* d_out, int out_size, void* d_ws, size_t ws_size,
                              hipStream_t stream) {
  const float* inp = (const float*)d_in[0];
  const float* tgt = (const float*)d_in[1];
  float* out = (float*)d_out;

  int N = out_size - 1;  // outputs: [loss scalar, match[N]]
  int D = in_sizes[0] / N;
  int M = in_sizes[1] / D;

  int Npad = ((N + BT - 1) / BT) * BT;
  int Mpad = ((M + BT - 1) / BT) * BT;
  int DP = ((D + 31) / 32) * 32;  // 192 for D=180
  int KPA = 3 * DP;               // 576 -> 1152-B rows (r9 layout)
  int gx = Mpad / BT, gy = Npad / BT;

  char* ws = (char*)d_ws;
  size_t off = 0;
  float* s_in = (float*)(ws + off); off += (size_t)N * 4;
  float* s_st = (float*)(ws + off); off += (size_t)M * 4;
  off = (off + 15) & ~(size_t)15;
  unsigned long long* sumbuf = (unsigned long long*)(ws + off); off += 16;
  unsigned long long* packed = (unsigned long long*)(ws + off); off += (size_t)N * 8;
  off = (off + 15) & ~(size_t)15;
  _Float16* Acat = (_Float16*)(ws + off); off += (size_t)Npad * KPA * 2;
  _Float16* Bcat = (_Float16*)(ws + off); off += (size_t)Mpad * KPA * 2;

  hipMemsetAsync(sumbuf, 0, 8, stream);

  int pgrid = Npad > Mpad ? Npad : Mpad;
  prep_kernel<<<pgrid, 64, 0, stream>>>(inp, tgt, Acat, Bcat, s_in, s_st,
                                        packed, N, M, Npad, Mpad, D, DP);

  const int ldsBytes = 4 * UNITH * 2;  // 64 KiB
  hipFuncSetAttribute((const void*)mfma_pair_min_kernel,
                      hipFuncAttributeMaxDynamicSharedMemorySize, ldsBytes);
  mfma_pair_min_kernel<<<gx * gy, 512, ldsBytes, stream>>>(
      Acat, Bcat, s_st, packed, N, M, KPA, gx);

  reduce_kernel<<<(N + 255) / 256, 256, 0, stream>>>(packed, s_in, out,
                                                     sumbuf, N);
  final_kernel<<<1, 64, 0, stream>>>(sumbuf, out, N);
}

// Round 18
// 203.314 us; speedup vs baseline: 1.0778x; 1.0778x over previous
//
#include <hip/hip_runtime.h>
#include <math.h>

#define EPSF 1e-8f

typedef _Float16 f16x8 __attribute__((ext_vector_type(8)));
typedef float f32x4 __attribute__((ext_vector_type(4)));

#define GLOAD_LDS16(g, l)                                                      \
  __builtin_amdgcn_global_load_lds(                                            \
      (const __attribute__((address_space(1))) unsigned int*)(g),              \
      (__attribute__((address_space(3))) unsigned int*)(l), 16, 0, 0)

#define WAITV(n) asm volatile("s_waitcnt vmcnt(" #n ")" ::: "memory")
#define BAR() __builtin_amdgcn_s_barrier()

__device__ __forceinline__ unsigned int ord_from_float(float f) {
  unsigned int u = __float_as_uint(f);
  return (u & 0x80000000u) ? ~u : (u | 0x80000000u);
}

__device__ __forceinline__ float float_from_ord(unsigned int o) {
  return (o & 0x80000000u) ? __uint_as_float(o & 0x7fffffffu)
                           : __uint_as_float(~o);
}

__device__ __forceinline__ unsigned long long shfl_xor_u64(unsigned long long x, int m) {
  int lo = __shfl_xor((int)(unsigned int)(x & 0xffffffffull), m, 64);
  int hi = __shfl_xor((int)(unsigned int)(x >> 32), m, 64);
  return ((unsigned long long)(unsigned int)hi << 32) | (unsigned int)lo;
}

// ---------------- merged prep kernel (vectorized, r9 padded layout) ----------------
// Segments padded to DP (=192), KPA = 3*DP = 576 (1152-B rows):
//   Acat row: [hi(log) @0 | hi(log) @DP | lo(log) @2DP], zeros in [D,DP) each
//   Bcat row: [hi(tgt) @0 | lo(tgt) @DP | hi(tgt) @2DP]
// Also: s_in (row sums), s_st (Stirling sums), packed init.
__global__ __launch_bounds__(64) void prep_kernel(
    const float* __restrict__ inp, const float* __restrict__ tgt,
    _Float16* __restrict__ Acat, _Float16* __restrict__ Bcat,
    float* __restrict__ s_in, float* __restrict__ s_st,
    unsigned long long* __restrict__ packed,
    int N, int M, int Npad, int Mpad, int D, int DP) {
  const int r = blockIdx.x;
  const int tid = threadIdx.x;
  const int KPA = 3 * DP;
  const int NC4 = D >> 2;  // exact float4 chunks (D=180 -> 45)
  float sa = 0.f, sb = 0.f;

  _Float16* const arow = (r < Npad) ? Acat + (size_t)r * KPA : nullptr;
  _Float16* const brow = (r < Mpad) ? Bcat + (size_t)r * KPA : nullptr;
  const float4* const ain = (const float4*)(inp + (size_t)r * D);
  const float4* const bin = (const float4*)(tgt + (size_t)r * D);

  for (int c = tid; c < NC4; c += 64) {
    if (arow) {
      float4 v = (r < N) ? ain[c] : make_float4(0.f, 0.f, 0.f, 0.f);
      float xs[4] = {v.x, v.y, v.z, v.w};
      #pragma unroll
      for (int e = 0; e < 4; ++e) {
        float x = xs[e];
        sa += x;
        float lg = (r < N) ? logf(x + EPSF) : 0.f;
        _Float16 h = (_Float16)lg;
        _Float16 l = (_Float16)(lg - (float)h);
        int d = c * 4 + e;
        arow[d] = h;
        arow[DP + d] = h;
        arow[2 * DP + d] = l;
      }
    }
    if (brow) {
      float4 v = (r < M) ? bin[c] : make_float4(0.f, 0.f, 0.f, 0.f);
      float xs[4] = {v.x, v.y, v.z, v.w};
      #pragma unroll
      for (int e = 0; e < 4; ++e) {
        float x = xs[e];
        if (x > 1.0f)
          sb += x * logf(x) - x + 0.5f * logf(6.283185307179586f * x);
        _Float16 h = (_Float16)x;
        _Float16 l = (_Float16)(x - (float)h);
        int d = c * 4 + e;
        brow[d] = h;
        brow[DP + d] = l;
        brow[2 * DP + d] = h;
      }
    }
  }
  // scalar remainder of [NC4*4, D) (none for D=180)
  for (int d = (NC4 << 2) + tid; d < D; d += 64) {
    if (arow) {
      float x = (r < N) ? inp[(size_t)r * D + d] : 0.f;
      sa += x;
      float lg = (r < N) ? logf(x + EPSF) : 0.f;
      _Float16 h = (_Float16)lg;
      _Float16 l = (_Float16)(lg - (float)h);
      arow[d] = h; arow[DP + d] = h; arow[2 * DP + d] = l;
    }
    if (brow) {
      float x = (r < M) ? tgt[(size_t)r * D + d] : 0.f;
      if (x > 1.0f)
        sb += x * logf(x) - x + 0.5f * logf(6.283185307179586f * x);
      _Float16 h = (_Float16)x;
      _Float16 l = (_Float16)(x - (float)h);
      brow[d] = h; brow[DP + d] = l; brow[2 * DP + d] = h;
    }
  }
  // zero the per-segment pad [D, DP) x 3 segments (DP-D = 12 for D=180)
  for (int d = D + tid; d < DP; d += 64) {
    if (arow) { arow[d] = (_Float16)0.f; arow[DP + d] = (_Float16)0.f; arow[2 * DP + d] = (_Float16)0.f; }
    if (brow) { brow[d] = (_Float16)0.f; brow[DP + d] = (_Float16)0.f; brow[2 * DP + d] = (_Float16)0.f; }
  }

  #pragma unroll
  for (int m = 1; m < 64; m <<= 1) {
    sa += __shfl_xor(sa, m, 64);
    sb += __shfl_xor(sb, m, 64);
  }
  if (tid == 0) {
    if (r < N) { s_in[r] = sa; packed[r] = ~0ull; }
    if (r < M) s_st[r] = sb;
  }
}

// ---------------- MFMA pair-min kernel (r9 core — fastest verified) ----------------
// 256x256 tile, 8 waves (2Mx4N), BK=32, 2 LDS buffers (64 KiB dynamic).
// Per step: STAGE(t+1, other buf) -> COMPUTE(t) -> WAITV(0) -> BAR.
#define BT 256
#define UNITH 8192  // halves per (buf,op) unit: 256 rows x 32 halves = 16 KB

__global__ __launch_bounds__(512, 2) void mfma_pair_min_kernel(
    const _Float16* __restrict__ Acat, const _Float16* __restrict__ Bcat,
    const float* __restrict__ s_st, unsigned long long* __restrict__ packed,
    int N, int M, int KPA, int gx) {
  extern __shared__ __align__(16) _Float16 smem[];  // 4 * UNITH = 64 KiB
  const int t = threadIdx.x;
  const int lane = t & 63;
  const int wid = t >> 6;   // 0..7
  const int wr = wid >> 2;  // 0..1 -> 128 output rows
  const int wc = wid & 3;   // 0..3 -> 64 output cols

  // XCD chunking + column-major traversal inside each chunk (round-6 verified)
  const int nwg = gridDim.x;
  const int q8 = nwg >> 3;
  const int xcd = blockIdx.x & 7;
  const int i8 = blockIdx.x >> 3;
  int brow, bcol;
  if (q8 % gx == 0) {
    int bh = q8 / gx;
    brow = xcd * bh + i8 % bh;
    bcol = i8 / bh;
  } else {
    int wg = xcd * q8 + i8;
    brow = wg / gx;
    bcol = wg % gx;
  }
  const int row0 = brow * BT;
  const int col0 = bcol * BT;

  f32x4 acc[8][4] = {};

  // Staging (round-3/4 verified swizzle): LDS dest linear; global source slot
  // pre-swizzled: LDS(r,s) = global(r, s^((r>>1)&3)). 0 bank conflicts.
  const int srow = lane >> 2;
  const int gs = (lane & 3) ^ ((lane >> 3) & 3);
  const _Float16* a0 = Acat + (size_t)(row0 + wid * 32 + srow) * KPA + gs * 8;
  const _Float16* a1 = a0 + (size_t)16 * KPA;
  const _Float16* b0 = Bcat + (size_t)(col0 + wid * 32 + srow) * KPA + gs * 8;
  const _Float16* b1 = b0 + (size_t)16 * KPA;

#define STAGE(buf_)                                                            \
  do {                                                                         \
    _Float16* dA_ = smem + (buf_) * 2 * UNITH + wid * 1024;                    \
    _Float16* dB_ = dA_ + UNITH;                                               \
    GLOAD_LDS16(a0, dA_);                                                      \
    GLOAD_LDS16(a1, dA_ + 512);                                                \
    GLOAD_LDS16(b0, dB_);                                                      \
    GLOAD_LDS16(b1, dB_ + 512);                                                \
  } while (0)

#define ADV() do { a0 += 32; a1 += 32; b0 += 32; b1 += 32; } while (0)

  const int rl = lane & 15;
  const int qq = lane >> 4;
  const int sa = qq ^ ((rl >> 1) & 3);  // swizzled k-slot

#define COMPUTE(buf_)                                                          \
  do {                                                                         \
    const _Float16* pA_ = smem + (buf_) * 2 * UNITH;                           \
    const _Float16* pB_ = pA_ + UNITH;                                         \
    f16x8 af[8], bf[4];                                                        \
    _Pragma("unroll")                                                          \
    for (int m = 0; m < 8; ++m)                                                \
      af[m] = *(const f16x8*)(pA_ + (wr * 128 + m * 16 + rl) * 32 + sa * 8);   \
    _Pragma("unroll")                                                          \
    for (int n = 0; n < 4; ++n)                                                \
      bf[n] = *(const f16x8*)(pB_ + (wc * 64 + n * 16 + rl) * 32 + sa * 8);    \
    __builtin_amdgcn_s_setprio(1);                                             \
    _Pragma("unroll")                                                          \
    for (int m = 0; m < 8; ++m)                                                \
      _Pragma("unroll")                                                        \
      for (int n = 0; n < 4; ++n)                                              \
        acc[m][n] = __builtin_amdgcn_mfma_f32_16x16x32_f16(af[m], bf[n],       \
                                                           acc[m][n], 0, 0, 0); \
    __builtin_amdgcn_s_setprio(0);                                             \
  } while (0)

  const int NT = KPA >> 5;  // 18 for D=180 (KPA=576)

  STAGE(0);
  WAITV(0);
  BAR();
  for (int kt = 0; kt < NT - 1; ++kt) {
    ADV();
    STAGE((kt + 1) & 1);  // issue next-step loads first (MFMA covers latency)
    COMPUTE(kt & 1);
    WAITV(0);             // own 4 loads landed; BAR syncs all waves' stages
    BAR();
  }
  COMPUTE((NT - 1) & 1);

#undef STAGE
#undef ADV
#undef COMPUTE

  // ---- fused min/argmin epilogue (atomicMin, verified) ----
  // C/D frag: col = lane&15, row = (lane>>4)*4 + reg   [guide §3, m89-verified]
  float stv[4];
  #pragma unroll
  for (int n = 0; n < 4; ++n) {
    int gj = col0 + wc * 64 + n * 16 + rl;
    stv[n] = (gj < M) ? s_st[gj] : __builtin_inff();
  }
  #pragma unroll
  for (int m = 0; m < 8; ++m) {
    #pragma unroll
    for (int g = 0; g < 4; ++g) {
      int grow = row0 + wr * 128 + m * 16 + qq * 4 + g;
      unsigned long long bst = ~0ull;
      #pragma unroll
      for (int n = 0; n < 4; ++n) {
        int gj = col0 + wc * 64 + n * 16 + rl;
        float val = stv[n] - acc[m][n][g];
        unsigned long long p =
            ((unsigned long long)ord_from_float(val) << 32) | (unsigned int)gj;
        if (p < bst) bst = p;
      }
      #pragma unroll
      for (int mm = 1; mm < 16; mm <<= 1) {
        unsigned long long o = shfl_xor_u64(bst, mm);
        if (o < bst) bst = o;
      }
      if (rl == 0 && grow < N) atomicMin(&packed[grow], bst);
    }
  }
}

// ---------------- reduce + final ----------------
__global__ __launch_bounds__(256) void reduce_kernel(
    const unsigned long long* __restrict__ packed,
    const float* __restrict__ s_in, float* __restrict__ out,
    unsigned long long* __restrict__ sumbuf, int N) {
  int i = blockIdx.x * 256 + threadIdx.x;
  double local = 0.0;
  if (i < N) {
    unsigned long long p = packed[i];
    out[1 + i] = (float)(unsigned int)(p & 0xffffffffull);
    float val = float_from_ord((unsigned int)(p >> 32));
    local = (double)(s_in[i] + val);
  }
  __shared__ double sh[256];
  sh[threadIdx.x] = local;
  __syncthreads();
  for (int o = 128; o > 0; o >>= 1) {
    if (threadIdx.x < o) sh[threadIdx.x] += sh[threadIdx.x + o];
    __syncthreads();
  }
  if (threadIdx.x == 0) {
    long long q = __double2ll_rn(sh[0] * 1048576.0);  // fixed-point: deterministic
    atomicAdd(sumbuf, (unsigned long long)q);
  }
}

__global__ void final_kernel(const unsigned long long* __restrict__ sumbuf,
                             float* __restrict__ out, int N) {
  if (threadIdx.x == 0)
    out[0] = (float)(((double)(long long)sumbuf[0] / 1048576.0) / (double)N);
}

extern "C" void kernel_launch(void* const* d_in, const int* in_sizes, int n_in,
                              void* d_out, int out_size, void* d_ws, size_t ws_size,
                              hipStream_t stream) {
  const float* inp = (const float*)d_in[0];
  const float* tgt = (const float*)d_in[1];
  float* out = (float*)d_out;

  int N = out_size - 1;  // outputs: [loss scalar, match[N]]
  int D = in_sizes[0] / N;
  int M = in_sizes[1] / D;

  int Npad = ((N + BT - 1) / BT) * BT;
  int Mpad = ((M + BT - 1) / BT) * BT;
  int DP = ((D + 31) / 32) * 32;  // 192 for D=180
  int KPA = 3 * DP;               // 576 -> 1152-B rows (r9 layout)
  int gx = Mpad / BT, gy = Npad / BT;

  // Workspace layout. CRITICAL: Acat/Bcat must be 256-B aligned — r17's
  // 16-B-aligned operands (sumbuf inserted before them) cost +25 µs in the
  // GEMM (every 64-B gload_lds source straddled cache lines).
  char* ws = (char*)d_ws;
  size_t off = 0;
  float* s_in = (float*)(ws + off); off += (size_t)N * 4;
  float* s_st = (float*)(ws + off); off += (size_t)M * 4;
  off = (off + 15) & ~(size_t)15;
  unsigned long long* packed = (unsigned long long*)(ws + off); off += (size_t)N * 8;
  off = (off + 15) & ~(size_t)15;
  unsigned long long* sumbuf = (unsigned long long*)(ws + off); off += 16;
  off = (off + 255) & ~(size_t)255;  // 256-B align operand panels
  _Float16* Acat = (_Float16*)(ws + off); off += (size_t)Npad * KPA * 2;
  off = (off + 255) & ~(size_t)255;
  _Float16* Bcat = (_Float16*)(ws + off); off += (size_t)Mpad * KPA * 2;

  hipMemsetAsync(sumbuf, 0, 8, stream);

  int pgrid = Npad > Mpad ? Npad : Mpad;
  prep_kernel<<<pgrid, 64, 0, stream>>>(inp, tgt, Acat, Bcat, s_in, s_st,
                                        packed, N, M, Npad, Mpad, D, DP);

  const int ldsBytes = 4 * UNITH * 2;  // 64 KiB
  hipFuncSetAttribute((const void*)mfma_pair_min_kernel,
                      hipFuncAttributeMaxDynamicSharedMemorySize, ldsBytes);
  mfma_pair_min_kernel<<<gx * gy, 512, ldsBytes, stream>>>(
      Acat, Bcat, s_st, packed, N, M, KPA, gx);

  reduce_kernel<<<(N + 255) / 256, 256, 0, stream>>>(packed, s_in, out,
                                                     sumbuf, N);
  final_kernel<<<1, 64, 0, stream>>>(sumbuf, out, N);
}

// Round 19
// 187.553 us; speedup vs baseline: 1.1684x; 1.0840x over previous
//
#include <hip/hip_runtime.h>
#include <math.h>

#define EPSF 1e-8f

typedef _Float16 f16x8 __attribute__((ext_vector_type(8)));
typedef float f32x4 __attribute__((ext_vector_type(4)));

#define GLOAD_LDS16(g, l)                                                      \
  __builtin_amdgcn_global_load_lds(                                            \
      (const __attribute__((address_space(1))) unsigned int*)(g),              \
      (__attribute__((address_space(3))) unsigned int*)(l), 16, 0, 0)

#define WAITV(n) asm volatile("s_waitcnt vmcnt(" #n ")" ::: "memory")
#define BAR() __builtin_amdgcn_s_barrier()

__device__ __forceinline__ unsigned int ord_from_float(float f) {
  unsigned int u = __float_as_uint(f);
  return (u & 0x80000000u) ? ~u : (u | 0x80000000u);
}

__device__ __forceinline__ float float_from_ord(unsigned int o) {
  return (o & 0x80000000u) ? __uint_as_float(o & 0x7fffffffu)
                           : __uint_as_float(~o);
}

__device__ __forceinline__ unsigned long long shfl_xor_u64(unsigned long long x, int m) {
  int lo = __shfl_xor((int)(unsigned int)(x & 0xffffffffull), m, 64);
  int hi = __shfl_xor((int)(unsigned int)(x >> 32), m, 64);
  return ((unsigned long long)(unsigned int)hi << 32) | (unsigned int)lo;
}

// ---------------- merged prep kernel (vectorized, r9 padded layout) ----------------
__global__ __launch_bounds__(64) void prep_kernel(
    const float* __restrict__ inp, const float* __restrict__ tgt,
    _Float16* __restrict__ Acat, _Float16* __restrict__ Bcat,
    float* __restrict__ s_in, float* __restrict__ s_st,
    unsigned long long* __restrict__ packed,
    int N, int M, int Npad, int Mpad, int D, int DP) {
  const int r = blockIdx.x;
  const int tid = threadIdx.x;
  const int KPA = 3 * DP;
  const int NC4 = D >> 2;
  float sa = 0.f, sb = 0.f;

  _Float16* const arow = (r < Npad) ? Acat + (size_t)r * KPA : nullptr;
  _Float16* const brow = (r < Mpad) ? Bcat + (size_t)r * KPA : nullptr;
  const float4* const ain = (const float4*)(inp + (size_t)r * D);
  const float4* const bin = (const float4*)(tgt + (size_t)r * D);

  for (int c = tid; c < NC4; c += 64) {
    if (arow) {
      float4 v = (r < N) ? ain[c] : make_float4(0.f, 0.f, 0.f, 0.f);
      float xs[4] = {v.x, v.y, v.z, v.w};
      #pragma unroll
      for (int e = 0; e < 4; ++e) {
        float x = xs[e];
        sa += x;
        float lg = (r < N) ? logf(x + EPSF) : 0.f;
        _Float16 h = (_Float16)lg;
        _Float16 l = (_Float16)(lg - (float)h);
        int d = c * 4 + e;
        arow[d] = h;
        arow[DP + d] = h;
        arow[2 * DP + d] = l;
      }
    }
    if (brow) {
      float4 v = (r < M) ? bin[c] : make_float4(0.f, 0.f, 0.f, 0.f);
      float xs[4] = {v.x, v.y, v.z, v.w};
      #pragma unroll
      for (int e = 0; e < 4; ++e) {
        float x = xs[e];
        if (x > 1.0f)
          sb += x * logf(x) - x + 0.5f * logf(6.283185307179586f * x);
        _Float16 h = (_Float16)x;
        _Float16 l = (_Float16)(x - (float)h);
        int d = c * 4 + e;
        brow[d] = h;
        brow[DP + d] = l;
        brow[2 * DP + d] = h;
      }
    }
  }
  for (int d = (NC4 << 2) + tid; d < D; d += 64) {
    if (arow) {
      float x = (r < N) ? inp[(size_t)r * D + d] : 0.f;
      sa += x;
      float lg = (r < N) ? logf(x + EPSF) : 0.f;
      _Float16 h = (_Float16)lg;
      _Float16 l = (_Float16)(lg - (float)h);
      arow[d] = h; arow[DP + d] = h; arow[2 * DP + d] = l;
    }
    if (brow) {
      float x = (r < M) ? tgt[(size_t)r * D + d] : 0.f;
      if (x > 1.0f)
        sb += x * logf(x) - x + 0.5f * logf(6.283185307179586f * x);
      _Float16 h = (_Float16)x;
      _Float16 l = (_Float16)(x - (float)h);
      brow[d] = h; brow[DP + d] = l; brow[2 * DP + d] = h;
    }
  }
  for (int d = D + tid; d < DP; d += 64) {
    if (arow) { arow[d] = (_Float16)0.f; arow[DP + d] = (_Float16)0.f; arow[2 * DP + d] = (_Float16)0.f; }
    if (brow) { brow[d] = (_Float16)0.f; brow[DP + d] = (_Float16)0.f; brow[2 * DP + d] = (_Float16)0.f; }
  }

  #pragma unroll
  for (int m = 1; m < 64; m <<= 1) {
    sa += __shfl_xor(sa, m, 64);
    sb += __shfl_xor(sb, m, 64);
  }
  if (tid == 0) {
    if (r < N) { s_in[r] = sa; packed[r] = ~0ull; }
    if (r < M) s_st[r] = sb;
  }
}

// ---------------- MFMA pair-min kernel: 256x256, 16 waves (4Mx4N) ----------------
// Same verified machinery as r9/r18 (gload_lds+pre-swizzled source, swizzled
// frag reads, 2 LDS bufs 64 KiB, WAITV(0)+BAR per step) but 16 waves of
// 64x64 -> ~118 regs/wave -> 4 waves/SIMD (2x intra-SIMD TLP vs r9's 2).
#define BT 256
#define UNITH 8192  // halves per (buf,op) unit: 256 rows x 32 halves = 16 KB

__global__ __launch_bounds__(1024) void mfma_pair_min_kernel(
    const _Float16* __restrict__ Acat, const _Float16* __restrict__ Bcat,
    const float* __restrict__ s_st, unsigned long long* __restrict__ packed,
    int N, int M, int KPA, int gx) {
  extern __shared__ __align__(16) _Float16 smem[];  // 4 * UNITH = 64 KiB
  const int t = threadIdx.x;
  const int lane = t & 63;
  const int wid = t >> 6;   // 0..15
  const int wr = wid >> 2;  // 0..3 -> 64 output rows each
  const int wc = wid & 3;   // 0..3 -> 64 output cols each

  // XCD chunking + column-major traversal inside each chunk (round-6 verified)
  const int nwg = gridDim.x;
  const int q8 = nwg >> 3;
  const int xcd = blockIdx.x & 7;
  const int i8 = blockIdx.x >> 3;
  int brow, bcol;
  if (q8 % gx == 0) {
    int bh = q8 / gx;
    brow = xcd * bh + i8 % bh;
    bcol = i8 / bh;
  } else {
    int wg = xcd * q8 + i8;
    brow = wg / gx;
    bcol = wg % gx;
  }
  const int row0 = brow * BT;
  const int col0 = bcol * BT;

  f32x4 acc[4][4] = {};

  // Staging: wave wid owns rows [wid*16, wid*16+16) of A and B per step
  // (1 gload_lds each). LDS dest linear; global source slot pre-swizzled:
  // LDS(r,s) = global(r, s^((r>>1)&3)) — swizzle depends on row&15 only,
  // so the 16-row-per-wave staging keeps the verified mapping (0 conflicts).
  const int srow = lane >> 2;
  const int gs = (lane & 3) ^ ((lane >> 3) & 3);
  const _Float16* a0 = Acat + (size_t)(row0 + wid * 16 + srow) * KPA + gs * 8;
  const _Float16* b0 = Bcat + (size_t)(col0 + wid * 16 + srow) * KPA + gs * 8;

#define STAGE(buf_)                                                            \
  do {                                                                         \
    _Float16* dA_ = smem + (buf_) * 2 * UNITH + wid * 512;                     \
    _Float16* dB_ = dA_ + UNITH;                                               \
    GLOAD_LDS16(a0, dA_);                                                      \
    GLOAD_LDS16(b0, dB_);                                                      \
  } while (0)

#define ADV() do { a0 += 32; b0 += 32; } while (0)

  const int rl = lane & 15;
  const int qq = lane >> 4;
  const int sa = qq ^ ((rl >> 1) & 3);  // swizzled k-slot

#define COMPUTE(buf_)                                                          \
  do {                                                                         \
    const _Float16* pA_ = smem + (buf_) * 2 * UNITH;                           \
    const _Float16* pB_ = pA_ + UNITH;                                         \
    f16x8 af[4], bf[4];                                                        \
    _Pragma("unroll")                                                          \
    for (int m = 0; m < 4; ++m)                                                \
      af[m] = *(const f16x8*)(pA_ + (wr * 64 + m * 16 + rl) * 32 + sa * 8);    \
    _Pragma("unroll")                                                          \
    for (int n = 0; n < 4; ++n)                                                \
      bf[n] = *(const f16x8*)(pB_ + (wc * 64 + n * 16 + rl) * 32 + sa * 8);    \
    __builtin_amdgcn_s_setprio(1);                                             \
    _Pragma("unroll")                                                          \
    for (int m = 0; m < 4; ++m)                                                \
      _Pragma("unroll")                                                        \
      for (int n = 0; n < 4; ++n)                                              \
        acc[m][n] = __builtin_amdgcn_mfma_f32_16x16x32_f16(af[m], bf[n],       \
                                                           acc[m][n], 0, 0, 0); \
    __builtin_amdgcn_s_setprio(0);                                             \
  } while (0)

  const int NT = KPA >> 5;  // 18 for D=180 (KPA=576)

  STAGE(0);
  WAITV(0);
  BAR();
  for (int kt = 0; kt < NT - 1; ++kt) {
    ADV();
    STAGE((kt + 1) & 1);  // issue next-step loads first (MFMA covers latency)
    COMPUTE(kt & 1);
    WAITV(0);             // own 2 loads landed; BAR syncs all waves' stages
    BAR();
  }
  COMPUTE((NT - 1) & 1);

#undef STAGE
#undef ADV
#undef COMPUTE

  // ---- fused min/argmin epilogue (atomicMin, verified) ----
  // C/D frag: col = lane&15, row = (lane>>4)*4 + reg   [guide §3, m89-verified]
  float stv[4];
  #pragma unroll
  for (int n = 0; n < 4; ++n) {
    int gj = col0 + wc * 64 + n * 16 + rl;
    stv[n] = (gj < M) ? s_st[gj] : __builtin_inff();
  }
  #pragma unroll
  for (int m = 0; m < 4; ++m) {
    #pragma unroll
    for (int g = 0; g < 4; ++g) {
      int grow = row0 + wr * 64 + m * 16 + qq * 4 + g;
      unsigned long long bst = ~0ull;
      #pragma unroll
      for (int n = 0; n < 4; ++n) {
        int gj = col0 + wc * 64 + n * 16 + rl;
        float val = stv[n] - acc[m][n][g];
        unsigned long long p =
            ((unsigned long long)ord_from_float(val) << 32) | (unsigned int)gj;
        if (p < bst) bst = p;
      }
      #pragma unroll
      for (int mm = 1; mm < 16; mm <<= 1) {
        unsigned long long o = shfl_xor_u64(bst, mm);
        if (o < bst) bst = o;
      }
      if (rl == 0 && grow < N) atomicMin(&packed[grow], bst);
    }
  }
}

// ---------------- reduce + final ----------------
__global__ __launch_bounds__(256) void reduce_kernel(
    const unsigned long long* __restrict__ packed,
    const float* __restrict__ s_in, float* __restrict__ out,
    unsigned long long* __restrict__ sumbuf, int N) {
  int i = blockIdx.x * 256 + threadIdx.x;
  double local = 0.0;
  if (i < N) {
    unsigned long long p = packed[i];
    out[1 + i] = (float)(unsigned int)(p & 0xffffffffull);
    float val = float_from_ord((unsigned int)(p >> 32));
    local = (double)(s_in[i] + val);
  }
  __shared__ double sh[256];
  sh[threadIdx.x] = local;
  __syncthreads();
  for (int o = 128; o > 0; o >>= 1) {
    if (threadIdx.x < o) sh[threadIdx.x] += sh[threadIdx.x + o];
    __syncthreads();
  }
  if (threadIdx.x == 0) {
    long long q = __double2ll_rn(sh[0] * 1048576.0);  // fixed-point: deterministic
    atomicAdd(sumbuf, (unsigned long long)q);
  }
}

__global__ void final_kernel(const unsigned long long* __restrict__ sumbuf,
                             float* __restrict__ out, int N) {
  if (threadIdx.x == 0)
    out[0] = (float)(((double)(long long)sumbuf[0] / 1048576.0) / (double)N);
}

extern "C" void kernel_launch(void* const* d_in, const int* in_sizes, int n_in,
                              void* d_out, int out_size, void* d_ws, size_t ws_size,
                              hipStream_t stream) {
  const float* inp = (const float*)d_in[0];
  const float* tgt = (const float*)d_in[1];
  float* out = (float*)d_out;

  int N = out_size - 1;  // outputs: [loss scalar, match[N]]
  int D = in_sizes[0] / N;
  int M = in_sizes[1] / D;

  int Npad = ((N + BT - 1) / BT) * BT;
  int Mpad = ((M + BT - 1) / BT) * BT;
  int DP = ((D + 31) / 32) * 32;  // 192 for D=180
  int KPA = 3 * DP;               // 576 -> 1152-B rows (r9 layout)
  int gx = Mpad / BT, gy = Npad / BT;

  // Workspace layout. CRITICAL (r17 lesson): Acat/Bcat must be 256-B aligned
  // — 16-B-aligned operands cost +25 µs (64-B gload_lds sources straddle
  // cache lines).
  char* ws = (char*)d_ws;
  size_t off = 0;
  float* s_in = (float*)(ws + off); off += (size_t)N * 4;
  float* s_st = (float*)(ws + off); off += (size_t)M * 4;
  off = (off + 15) & ~(size_t)15;
  unsigned long long* packed = (unsigned long long*)(ws + off); off += (size_t)N * 8;
  off = (off + 15) & ~(size_t)15;
  unsigned long long* sumbuf = (unsigned long long*)(ws + off); off += 16;
  off = (off + 255) & ~(size_t)255;
  _Float16* Acat = (_Float16*)(ws + off); off += (size_t)Npad * KPA * 2;
  off = (off + 255) & ~(size_t)255;
  _Float16* Bcat = (_Float16*)(ws + off); off += (size_t)Mpad * KPA * 2;

  hipMemsetAsync(sumbuf, 0, 8, stream);

  int pgrid = Npad > Mpad ? Npad : Mpad;
  prep_kernel<<<pgrid, 64, 0, stream>>>(inp, tgt, Acat, Bcat, s_in, s_st,
                                        packed, N, M, Npad, Mpad, D, DP);

  const int ldsBytes = 4 * UNITH * 2;  // 64 KiB
  hipFuncSetAttribute((const void*)mfma_pair_min_kernel,
                      hipFuncAttributeMaxDynamicSharedMemorySize, ldsBytes);
  mfma_pair_min_kernel<<<gx * gy, 1024, ldsBytes, stream>>>(
      Acat, Bcat, s_st, packed, N, M, KPA, gx);

  reduce_kernel<<<(N + 255) / 256, 256, 0, stream>>>(packed, s_in, out,
                                                     sumbuf, N);
  final_kernel<<<1, 64, 0, stream>>>(sumbuf, out, N);
}

// Round 20
// 180.731 us; speedup vs baseline: 1.2125x; 1.0377x over previous
//
#include <hip/hip_runtime.h>
#include <math.h>

#define EPSF 1e-8f

typedef _Float16 f16x8 __attribute__((ext_vector_type(8)));
typedef float f32x4 __attribute__((ext_vector_type(4)));

#define GLOAD_LDS16(g, l)                                                      \
  __builtin_amdgcn_global_load_lds(                                            \
      (const __attribute__((address_space(1))) unsigned int*)(g),              \
      (__attribute__((address_space(3))) unsigned int*)(l), 16, 0, 0)

#define WAITV(n) asm volatile("s_waitcnt vmcnt(" #n ")" ::: "memory")
#define BAR() __builtin_amdgcn_s_barrier()

__device__ __forceinline__ unsigned int ord_from_float(float f) {
  unsigned int u = __float_as_uint(f);
  return (u & 0x80000000u) ? ~u : (u | 0x80000000u);
}

__device__ __forceinline__ float float_from_ord(unsigned int o) {
  return (o & 0x80000000u) ? __uint_as_float(o & 0x7fffffffu)
                           : __uint_as_float(~o);
}

__device__ __forceinline__ unsigned long long shfl_xor_u64(unsigned long long x, int m) {
  int lo = __shfl_xor((int)(unsigned int)(x & 0xffffffffull), m, 64);
  int hi = __shfl_xor((int)(unsigned int)(x >> 32), m, 64);
  return ((unsigned long long)(unsigned int)hi << 32) | (unsigned int)lo;
}

// ---------------- merged prep kernel (vectorized, r9 padded layout) ----------------
__global__ __launch_bounds__(64) void prep_kernel(
    const float* __restrict__ inp, const float* __restrict__ tgt,
    _Float16* __restrict__ Acat, _Float16* __restrict__ Bcat,
    float* __restrict__ s_in, float* __restrict__ s_st,
    unsigned long long* __restrict__ packed,
    int N, int M, int Npad, int Mpad, int D, int DP) {
  const int r = blockIdx.x;
  const int tid = threadIdx.x;
  const int KPA = 3 * DP;
  const int NC4 = D >> 2;
  float sa = 0.f, sb = 0.f;

  _Float16* const arow = (r < Npad) ? Acat + (size_t)r * KPA : nullptr;
  _Float16* const brow = (r < Mpad) ? Bcat + (size_t)r * KPA : nullptr;
  const float4* const ain = (const float4*)(inp + (size_t)r * D);
  const float4* const bin = (const float4*)(tgt + (size_t)r * D);

  for (int c = tid; c < NC4; c += 64) {
    if (arow) {
      float4 v = (r < N) ? ain[c] : make_float4(0.f, 0.f, 0.f, 0.f);
      float xs[4] = {v.x, v.y, v.z, v.w};
      #pragma unroll
      for (int e = 0; e < 4; ++e) {
        float x = xs[e];
        sa += x;
        float lg = (r < N) ? logf(x + EPSF) : 0.f;
        _Float16 h = (_Float16)lg;
        _Float16 l = (_Float16)(lg - (float)h);
        int d = c * 4 + e;
        arow[d] = h;
        arow[DP + d] = h;
        arow[2 * DP + d] = l;
      }
    }
    if (brow) {
      float4 v = (r < M) ? bin[c] : make_float4(0.f, 0.f, 0.f, 0.f);
      float xs[4] = {v.x, v.y, v.z, v.w};
      #pragma unroll
      for (int e = 0; e < 4; ++e) {
        float x = xs[e];
        if (x > 1.0f)
          sb += x * logf(x) - x + 0.5f * logf(6.283185307179586f * x);
        _Float16 h = (_Float16)x;
        _Float16 l = (_Float16)(x - (float)h);
        int d = c * 4 + e;
        brow[d] = h;
        brow[DP + d] = l;
        brow[2 * DP + d] = h;
      }
    }
  }
  for (int d = (NC4 << 2) + tid; d < D; d += 64) {
    if (arow) {
      float x = (r < N) ? inp[(size_t)r * D + d] : 0.f;
      sa += x;
      float lg = (r < N) ? logf(x + EPSF) : 0.f;
      _Float16 h = (_Float16)lg;
      _Float16 l = (_Float16)(lg - (float)h);
      arow[d] = h; arow[DP + d] = h; arow[2 * DP + d] = l;
    }
    if (brow) {
      float x = (r < M) ? tgt[(size_t)r * D + d] : 0.f;
      if (x > 1.0f)
        sb += x * logf(x) - x + 0.5f * logf(6.283185307179586f * x);
      _Float16 h = (_Float16)x;
      _Float16 l = (_Float16)(x - (float)h);
      brow[d] = h; brow[DP + d] = l; brow[2 * DP + d] = h;
    }
  }
  for (int d = D + tid; d < DP; d += 64) {
    if (arow) { arow[d] = (_Float16)0.f; arow[DP + d] = (_Float16)0.f; arow[2 * DP + d] = (_Float16)0.f; }
    if (brow) { brow[d] = (_Float16)0.f; brow[DP + d] = (_Float16)0.f; brow[2 * DP + d] = (_Float16)0.f; }
  }

  #pragma unroll
  for (int m = 1; m < 64; m <<= 1) {
    sa += __shfl_xor(sa, m, 64);
    sb += __shfl_xor(sb, m, 64);
  }
  if (tid == 0) {
    if (r < N) { s_in[r] = sa; packed[r] = ~0ull; }
    if (r < M) s_st[r] = sb;
  }
}

// ---------------- MFMA pair-min kernel: 256x256, 16 waves, BK=64 ----------------
// r19 structure (16 waves of 64x64, 4 waves/SIMD) with BK doubled to 64:
// 9 K-steps instead of 18 -> half the WAITV(0)+BAR drains. LDS = 2 bufs x
// (256 rows x 64 halves) x 2 ops = 128 KiB dynamic (regs pin 1 block/CU
// anyway). Swizzle generalized to 8 slots/row: LDS(r,s) = global(r, s^(r&7));
// read slot (c*4+qq)^(rl&7) -> 2-way bank aliasing (free, m136).
#define BT 256
#define UNITH 16384  // halves per (buf,op) unit: 256 rows x 64 halves = 32 KB

__global__ __launch_bounds__(1024) void mfma_pair_min_kernel(
    const _Float16* __restrict__ Acat, const _Float16* __restrict__ Bcat,
    const float* __restrict__ s_st, unsigned long long* __restrict__ packed,
    int N, int M, int KPA, int gx) {
  extern __shared__ __align__(16) _Float16 smem[];  // 4 * UNITH = 128 KiB
  const int t = threadIdx.x;
  const int lane = t & 63;
  const int wid = t >> 6;   // 0..15
  const int wr = wid >> 2;  // 0..3 -> 64 output rows each
  const int wc = wid & 3;   // 0..3 -> 64 output cols each

  // XCD chunking + column-major traversal inside each chunk (round-6 verified)
  const int nwg = gridDim.x;
  const int q8 = nwg >> 3;
  const int xcd = blockIdx.x & 7;
  const int i8 = blockIdx.x >> 3;
  int brow, bcol;
  if (q8 % gx == 0) {
    int bh = q8 / gx;
    brow = xcd * bh + i8 % bh;
    bcol = i8 / bh;
  } else {
    int wg = xcd * q8 + i8;
    brow = wg / gx;
    bcol = wg % gx;
  }
  const int row0 = brow * BT;
  const int col0 = bcol * BT;

  f32x4 acc[4][4] = {};

  // Staging (BK=64): wave wid owns rows [wid*16, +16) of A and B per step;
  // 2 gload_lds per operand (8 rows of 128 B each). LDS dest linear
  // (lane l -> row l>>3, slot l&7); global source slot pre-swizzled:
  // gs = (lane&7) ^ (lane>>3)  =>  LDS(r,s) = global(r, s^(r&7)).
  const int srow = lane >> 3;                    // 0..7
  const int gs = (lane & 7) ^ (lane >> 3);
  const _Float16* a0 = Acat + (size_t)(row0 + wid * 16 + srow) * KPA + gs * 8;
  const _Float16* a1 = a0 + (size_t)8 * KPA;
  const _Float16* b0 = Bcat + (size_t)(col0 + wid * 16 + srow) * KPA + gs * 8;
  const _Float16* b1 = b0 + (size_t)8 * KPA;

#define STAGE(buf_)                                                            \
  do {                                                                         \
    _Float16* dA_ = smem + (buf_) * 2 * UNITH + wid * 1024;                    \
    _Float16* dB_ = dA_ + UNITH;                                               \
    GLOAD_LDS16(a0, dA_);                                                      \
    GLOAD_LDS16(a1, dA_ + 512);                                                \
    GLOAD_LDS16(b0, dB_);                                                      \
    GLOAD_LDS16(b1, dB_ + 512);                                                \
  } while (0)

#define ADV() do { a0 += 64; a1 += 64; b0 += 64; b1 += 64; } while (0)

  const int rl = lane & 15;
  const int qq = lane >> 4;

  // per-chunk swizzled slot: chunk c (k in [c*32,(c+1)*32)), row r:
  // slot = (c*4 + qq) ^ (r&7); r&7 == rl&7 for all frag rows.
  const int s0 = (0 * 4 + qq) ^ (rl & 7);
  const int s1 = (1 * 4 + qq) ^ (rl & 7);

#define COMPUTE(buf_)                                                          \
  do {                                                                         \
    const _Float16* pA_ = smem + (buf_) * 2 * UNITH;                           \
    const _Float16* pB_ = pA_ + UNITH;                                         \
    f16x8 af[4], bf[4];                                                        \
    /* chunk 0 */                                                              \
    _Pragma("unroll")                                                          \
    for (int m = 0; m < 4; ++m)                                                \
      af[m] = *(const f16x8*)(pA_ + (wr * 64 + m * 16 + rl) * 64 + s0 * 8);    \
    _Pragma("unroll")                                                          \
    for (int n = 0; n < 4; ++n)                                                \
      bf[n] = *(const f16x8*)(pB_ + (wc * 64 + n * 16 + rl) * 64 + s0 * 8);    \
    __builtin_amdgcn_s_setprio(1);                                             \
    _Pragma("unroll")                                                          \
    for (int m = 0; m < 4; ++m)                                                \
      _Pragma("unroll")                                                        \
      for (int n = 0; n < 4; ++n)                                              \
        acc[m][n] = __builtin_amdgcn_mfma_f32_16x16x32_f16(af[m], bf[n],       \
                                                           acc[m][n], 0, 0, 0); \
    __builtin_amdgcn_s_setprio(0);                                             \
    /* chunk 1 */                                                              \
    _Pragma("unroll")                                                          \
    for (int m = 0; m < 4; ++m)                                                \
      af[m] = *(const f16x8*)(pA_ + (wr * 64 + m * 16 + rl) * 64 + s1 * 8);    \
    _Pragma("unroll")                                                          \
    for (int n = 0; n < 4; ++n)                                                \
      bf[n] = *(const f16x8*)(pB_ + (wc * 64 + n * 16 + rl) * 64 + s1 * 8);    \
    __builtin_amdgcn_s_setprio(1);                                             \
    _Pragma("unroll")                                                          \
    for (int m = 0; m < 4; ++m)                                                \
      _Pragma("unroll")                                                        \
      for (int n = 0; n < 4; ++n)                                              \
        acc[m][n] = __builtin_amdgcn_mfma_f32_16x16x32_f16(af[m], bf[n],       \
                                                           acc[m][n], 0, 0, 0); \
    __builtin_amdgcn_s_setprio(0);                                             \
  } while (0)

  const int NT = KPA >> 6;  // 9 for D=180 (KPA=576)

  STAGE(0);
  WAITV(0);
  BAR();
  for (int kt = 0; kt < NT - 1; ++kt) {
    ADV();
    STAGE((kt + 1) & 1);  // issue next-step loads first (MFMA covers latency)
    COMPUTE(kt & 1);
    WAITV(0);             // own 4 loads landed; BAR syncs all waves' stages
    BAR();
  }
  COMPUTE((NT - 1) & 1);

#undef STAGE
#undef ADV
#undef COMPUTE

  // ---- fused min/argmin epilogue (atomicMin, verified) ----
  // C/D frag: col = lane&15, row = (lane>>4)*4 + reg   [guide §3, m89-verified]
  float stv[4];
  #pragma unroll
  for (int n = 0; n < 4; ++n) {
    int gj = col0 + wc * 64 + n * 16 + rl;
    stv[n] = (gj < M) ? s_st[gj] : __builtin_inff();
  }
  #pragma unroll
  for (int m = 0; m < 4; ++m) {
    #pragma unroll
    for (int g = 0; g < 4; ++g) {
      int grow = row0 + wr * 64 + m * 16 + qq * 4 + g;
      unsigned long long bst = ~0ull;
      #pragma unroll
      for (int n = 0; n < 4; ++n) {
        int gj = col0 + wc * 64 + n * 16 + rl;
        float val = stv[n] - acc[m][n][g];
        unsigned long long p =
            ((unsigned long long)ord_from_float(val) << 32) | (unsigned int)gj;
        if (p < bst) bst = p;
      }
      #pragma unroll
      for (int mm = 1; mm < 16; mm <<= 1) {
        unsigned long long o = shfl_xor_u64(bst, mm);
        if (o < bst) bst = o;
      }
      if (rl == 0 && grow < N) atomicMin(&packed[grow], bst);
    }
  }
}

// ---------------- reduce + final ----------------
__global__ __launch_bounds__(256) void reduce_kernel(
    const unsigned long long* __restrict__ packed,
    const float* __restrict__ s_in, float* __restrict__ out,
    unsigned long long* __restrict__ sumbuf, int N) {
  int i = blockIdx.x * 256 + threadIdx.x;
  double local = 0.0;
  if (i < N) {
    unsigned long long p = packed[i];
    out[1 + i] = (float)(unsigned int)(p & 0xffffffffull);
    float val = float_from_ord((unsigned int)(p >> 32));
    local = (double)(s_in[i] + val);
  }
  __shared__ double sh[256];
  sh[threadIdx.x] = local;
  __syncthreads();
  for (int o = 128; o > 0; o >>= 1) {
    if (threadIdx.x < o) sh[threadIdx.x] += sh[threadIdx.x + o];
    __syncthreads();
  }
  if (threadIdx.x == 0) {
    long long q = __double2ll_rn(sh[0] * 1048576.0);  // fixed-point: deterministic
    atomicAdd(sumbuf, (unsigned long long)q);
  }
}

__global__ void final_kernel(const unsigned long long* __restrict__ sumbuf,
                             float* __restrict__ out, int N) {
  if (threadIdx.x == 0)
    out[0] = (float)(((double)(long long)sumbuf[0] / 1048576.0) / (double)N);
}

extern "C" void kernel_launch(void* const* d_in, const int* in_sizes, int n_in,
                              void* d_out, int out_size, void* d_ws, size_t ws_size,
                              hipStream_t stream) {
  const float* inp = (const float*)d_in[0];
  const float* tgt = (const float*)d_in[1];
  float* out = (float*)d_out;

  int N = out_size - 1;  // outputs: [loss scalar, match[N]]
  int D = in_sizes[0] / N;
  int M = in_sizes[1] / D;

  int Npad = ((N + BT - 1) / BT) * BT;
  int Mpad = ((M + BT - 1) / BT) * BT;
  int DP = ((D + 31) / 32) * 32;  // 192 for D=180
  int KPA = 3 * DP;               // 576 -> 9 K-tiles of 64
  int gx = Mpad / BT, gy = Npad / BT;

  // Workspace layout. CRITICAL (r17 lesson): Acat/Bcat must be 256-B aligned.
  char* ws = (char*)d_ws;
  size_t off = 0;
  float* s_in = (float*)(ws + off); off += (size_t)N * 4;
  float* s_st = (float*)(ws + off); off += (size_t)M * 4;
  off = (off + 15) & ~(size_t)15;
  unsigned long long* packed = (unsigned long long*)(ws + off); off += (size_t)N * 8;
  off = (off + 15) & ~(size_t)15;
  unsigned long long* sumbuf = (unsigned long long*)(ws + off); off += 16;
  off = (off + 255) & ~(size_t)255;
  _Float16* Acat = (_Float16*)(ws + off); off += (size_t)Npad * KPA * 2;
  off = (off + 255) & ~(size_t)255;
  _Float16* Bcat = (_Float16*)(ws + off); off += (size_t)Mpad * KPA * 2;

  hipMemsetAsync(sumbuf, 0, 8, stream);

  int pgrid = Npad > Mpad ? Npad : Mpad;
  prep_kernel<<<pgrid, 64, 0, stream>>>(inp, tgt, Acat, Bcat, s_in, s_st,
                                        packed, N, M, Npad, Mpad, D, DP);

  const int ldsBytes = 4 * UNITH * 2;  // 128 KiB
  hipFuncSetAttribute((const void*)mfma_pair_min_kernel,
                      hipFuncAttributeMaxDynamicSharedMemorySize, ldsBytes);
  mfma_pair_min_kernel<<<gx * gy, 1024, ldsBytes, stream>>>(
      Acat, Bcat, s_st, packed, N, M, KPA, gx);

  reduce_kernel<<<(N + 255) / 256, 256, 0, stream>>>(packed, s_in, out,
                                                     sumbuf, N);
  final_kernel<<<1, 64, 0, stream>>>(sumbuf, out, N);
}

// Round 21
// 178.010 us; speedup vs baseline: 1.2310x; 1.0153x over previous
//
#include <hip/hip_runtime.h>
#include <math.h>

#define EPSF 1e-8f

typedef _Float16 f16x8 __attribute__((ext_vector_type(8)));
typedef float f32x4 __attribute__((ext_vector_type(4)));

#define GLOAD_LDS16(g, l)                                                      \
  __builtin_amdgcn_global_load_lds(                                            \
      (const __attribute__((address_space(1))) unsigned int*)(g),              \
      (__attribute__((address_space(3))) unsigned int*)(l), 16, 0, 0)

#define WAITV(n) asm volatile("s_waitcnt vmcnt(" #n ")" ::: "memory")
#define BAR() __builtin_amdgcn_s_barrier()

__device__ __forceinline__ unsigned int ord_from_float(float f) {
  unsigned int u = __float_as_uint(f);
  return (u & 0x80000000u) ? ~u : (u | 0x80000000u);
}

__device__ __forceinline__ float float_from_ord(unsigned int o) {
  return (o & 0x80000000u) ? __uint_as_float(o & 0x7fffffffu)
                           : __uint_as_float(~o);
}

__device__ __forceinline__ unsigned long long shfl_xor_u64(unsigned long long x, int m) {
  int lo = __shfl_xor((int)(unsigned int)(x & 0xffffffffull), m, 64);
  int hi = __shfl_xor((int)(unsigned int)(x >> 32), m, 64);
  return ((unsigned long long)(unsigned int)hi << 32) | (unsigned int)lo;
}

// ---------------- merged prep kernel ----------------
// Acat row (stride 2*DP): [hi(log) @0 | lo(log) @DP]  (hi seg deduped — the
// GEMM revisits it), zeros in [D,DP). Bcat row (stride 3*DP):
// [hi(tgt) | lo(tgt) | hi(tgt)]. Also s_in, s_st, packed-init.
__global__ __launch_bounds__(64) void prep_kernel(
    const float* __restrict__ inp, const float* __restrict__ tgt,
    _Float16* __restrict__ Acat, _Float16* __restrict__ Bcat,
    float* __restrict__ s_in, float* __restrict__ s_st,
    unsigned long long* __restrict__ packed,
    int N, int M, int Npad, int Mpad, int D, int DP) {
  const int r = blockIdx.x;
  const int tid = threadIdx.x;
  const int NC4 = D >> 2;
  float sa = 0.f, sb = 0.f;

  _Float16* const arow = (r < Npad) ? Acat + (size_t)r * (2 * DP) : nullptr;
  _Float16* const brow = (r < Mpad) ? Bcat + (size_t)r * (3 * DP) : nullptr;
  const float4* const ain = (const float4*)(inp + (size_t)r * D);
  const float4* const bin = (const float4*)(tgt + (size_t)r * D);

  for (int c = tid; c < NC4; c += 64) {
    if (arow) {
      float4 v = (r < N) ? ain[c] : make_float4(0.f, 0.f, 0.f, 0.f);
      float xs[4] = {v.x, v.y, v.z, v.w};
      #pragma unroll
      for (int e = 0; e < 4; ++e) {
        float x = xs[e];
        sa += x;
        float lg = (r < N) ? logf(x + EPSF) : 0.f;
        _Float16 h = (_Float16)lg;
        _Float16 l = (_Float16)(lg - (float)h);
        int d = c * 4 + e;
        arow[d] = h;
        arow[DP + d] = l;
      }
    }
    if (brow) {
      float4 v = (r < M) ? bin[c] : make_float4(0.f, 0.f, 0.f, 0.f);
      float xs[4] = {v.x, v.y, v.z, v.w};
      #pragma unroll
      for (int e = 0; e < 4; ++e) {
        float x = xs[e];
        if (x > 1.0f)
          sb += x * logf(x) - x + 0.5f * logf(6.283185307179586f * x);
        _Float16 h = (_Float16)x;
        _Float16 l = (_Float16)(x - (float)h);
        int d = c * 4 + e;
        brow[d] = h;
        brow[DP + d] = l;
        brow[2 * DP + d] = h;
      }
    }
  }
  for (int d = (NC4 << 2) + tid; d < D; d += 64) {
    if (arow) {
      float x = (r < N) ? inp[(size_t)r * D + d] : 0.f;
      sa += x;
      float lg = (r < N) ? logf(x + EPSF) : 0.f;
      _Float16 h = (_Float16)lg;
      _Float16 l = (_Float16)(lg - (float)h);
      arow[d] = h; arow[DP + d] = l;
    }
    if (brow) {
      float x = (r < M) ? tgt[(size_t)r * D + d] : 0.f;
      if (x > 1.0f)
        sb += x * logf(x) - x + 0.5f * logf(6.283185307179586f * x);
      _Float16 h = (_Float16)x;
      _Float16 l = (_Float16)(x - (float)h);
      brow[d] = h; brow[DP + d] = l; brow[2 * DP + d] = h;
    }
  }
  for (int d = D + tid; d < DP; d += 64) {
    if (arow) { arow[d] = (_Float16)0.f; arow[DP + d] = (_Float16)0.f; }
    if (brow) { brow[d] = (_Float16)0.f; brow[DP + d] = (_Float16)0.f; brow[2 * DP + d] = (_Float16)0.f; }
  }

  #pragma unroll
  for (int m = 1; m < 64; m <<= 1) {
    sa += __shfl_xor(sa, m, 64);
    sb += __shfl_xor(sb, m, 64);
  }
  if (tid == 0) {
    if (r < N) { s_in[r] = sa; packed[r] = ~0ull; }
    if (r < M) s_st[r] = sb;
  }
}

// ---------------- MFMA pair-min kernel: 256x256, 16 waves, BK=64 ----------------
// r20 structure (verified: 16 waves of 64x64, 4 waves/SIMD, BK=64, 2 LDS bufs
// 128 KiB, WAITV(0)+BAR per step, 8-slot swizzle). A walked with the deduped
// [hi|lo] layout: step kt reads A k-offset ka = (kt<SEG ? kt : kt-SEG)*64,
// pairing (Ahi.Bhi)x3, (Ahi.Blo)x3, (Alo.Bhi)x3 — identical products to r20.
#define BT 256
#define UNITH 16384  // halves per (buf,op) unit: 256 rows x 64 halves = 32 KB

__global__ __launch_bounds__(1024) void mfma_pair_min_kernel(
    const _Float16* __restrict__ Acat, const _Float16* __restrict__ Bcat,
    const float* __restrict__ s_st, unsigned long long* __restrict__ packed,
    int N, int M, int DP, int gx) {
  extern __shared__ __align__(16) _Float16 smem[];  // 4 * UNITH = 128 KiB
  const int t = threadIdx.x;
  const int lane = t & 63;
  const int wid = t >> 6;   // 0..15
  const int wr = wid >> 2;  // 0..3 -> 64 output rows each
  const int wc = wid & 3;   // 0..3 -> 64 output cols each
  const int KPA_A = 2 * DP;
  const int KPA_B = 3 * DP;

  // XCD chunking + column-major traversal inside each chunk (round-6 verified)
  const int nwg = gridDim.x;
  const int q8 = nwg >> 3;
  const int xcd = blockIdx.x & 7;
  const int i8 = blockIdx.x >> 3;
  int brow, bcol;
  if (q8 % gx == 0) {
    int bh = q8 / gx;
    brow = xcd * bh + i8 % bh;
    bcol = i8 / bh;
  } else {
    int wg = xcd * q8 + i8;
    brow = wg / gx;
    bcol = wg % gx;
  }
  const int row0 = brow * BT;
  const int col0 = bcol * BT;

  f32x4 acc[4][4] = {};

  // Staging (BK=64, verified r20): wave wid owns rows [wid*16,+16); 2 gload_lds
  // per operand (8 rows x 128 B). LDS dest linear (lane -> row l>>3, slot l&7);
  // global source slot pre-swizzled: gs = (lane&7)^(lane>>3)
  // => LDS(r,s) = global(r, s^(r&7)).
  const int srow = lane >> 3;
  const int gs = (lane & 7) ^ (lane >> 3);
  const _Float16* const aB0 = Acat + (size_t)(row0 + wid * 16 + srow) * KPA_A + gs * 8;
  const _Float16* const aB1 = aB0 + (size_t)8 * KPA_A;
  const _Float16* const bB0 = Bcat + (size_t)(col0 + wid * 16 + srow) * KPA_B + gs * 8;
  const _Float16* const bB1 = bB0 + (size_t)8 * KPA_B;
  const int SEG = DP >> 6;  // K-steps per segment (3 for D=180)

#define STAGE(buf_, kt_)                                                       \
  do {                                                                         \
    const int ka_ = ((kt_) < SEG ? (kt_) : (kt_) - SEG) * 64;                  \
    const int kb_ = (kt_) * 64;                                                \
    _Float16* dA_ = smem + (buf_) * 2 * UNITH + wid * 1024;                    \
    _Float16* dB_ = dA_ + UNITH;                                               \
    GLOAD_LDS16(aB0 + ka_, dA_);                                               \
    GLOAD_LDS16(aB1 + ka_, dA_ + 512);                                         \
    GLOAD_LDS16(bB0 + kb_, dB_);                                               \
    GLOAD_LDS16(bB1 + kb_, dB_ + 512);                                         \
  } while (0)

  const int rl = lane & 15;
  const int qq = lane >> 4;
  const int s0 = (0 * 4 + qq) ^ (rl & 7);  // chunk-0 swizzled slot
  const int s1 = (1 * 4 + qq) ^ (rl & 7);  // chunk-1

#define COMPUTE(buf_)                                                          \
  do {                                                                         \
    const _Float16* pA_ = smem + (buf_) * 2 * UNITH;                           \
    const _Float16* pB_ = pA_ + UNITH;                                         \
    f16x8 af[4], bf[4];                                                        \
    _Pragma("unroll")                                                          \
    for (int m = 0; m < 4; ++m)                                                \
      af[m] = *(const f16x8*)(pA_ + (wr * 64 + m * 16 + rl) * 64 + s0 * 8);    \
    _Pragma("unroll")                                                          \
    for (int n = 0; n < 4; ++n)                                                \
      bf[n] = *(const f16x8*)(pB_ + (wc * 64 + n * 16 + rl) * 64 + s0 * 8);    \
    __builtin_amdgcn_s_setprio(1);                                             \
    _Pragma("unroll")                                                          \
    for (int m = 0; m < 4; ++m)                                                \
      _Pragma("unroll")                                                        \
      for (int n = 0; n < 4; ++n)                                              \
        acc[m][n] = __builtin_amdgcn_mfma_f32_16x16x32_f16(af[m], bf[n],       \
                                                           acc[m][n], 0, 0, 0); \
    __builtin_amdgcn_s_setprio(0);                                             \
    _Pragma("unroll")                                                          \
    for (int m = 0; m < 4; ++m)                                                \
      af[m] = *(const f16x8*)(pA_ + (wr * 64 + m * 16 + rl) * 64 + s1 * 8);    \
    _Pragma("unroll")                                                          \
    for (int n = 0; n < 4; ++n)                                                \
      bf[n] = *(const f16x8*)(pB_ + (wc * 64 + n * 16 + rl) * 64 + s1 * 8);    \
    __builtin_amdgcn_s_setprio(1);                                             \
    _Pragma("unroll")                                                          \
    for (int m = 0; m < 4; ++m)                                                \
      _Pragma("unroll")                                                        \
      for (int n = 0; n < 4; ++n)                                              \
        acc[m][n] = __builtin_amdgcn_mfma_f32_16x16x32_f16(af[m], bf[n],       \
                                                           acc[m][n], 0, 0, 0); \
    __builtin_amdgcn_s_setprio(0);                                             \
  } while (0)

  const int NT = 3 * SEG;  // 9 for D=180

  STAGE(0, 0);
  WAITV(0);
  BAR();
  for (int kt = 0; kt < NT - 1; ++kt) {
    STAGE((kt + 1) & 1, kt + 1);  // issue next-step loads first
    COMPUTE(kt & 1);
    WAITV(0);
    BAR();
  }
  COMPUTE((NT - 1) & 1);

#undef STAGE
#undef COMPUTE

  // ---- fused min/argmin epilogue (atomicMin, verified) ----
  // C/D frag: col = lane&15, row = (lane>>4)*4 + reg   [guide §3, m89-verified]
  float stv[4];
  #pragma unroll
  for (int n = 0; n < 4; ++n) {
    int gj = col0 + wc * 64 + n * 16 + rl;
    stv[n] = (gj < M) ? s_st[gj] : __builtin_inff();
  }
  #pragma unroll
  for (int m = 0; m < 4; ++m) {
    #pragma unroll
    for (int g = 0; g < 4; ++g) {
      int grow = row0 + wr * 64 + m * 16 + qq * 4 + g;
      unsigned long long bst = ~0ull;
      #pragma unroll
      for (int n = 0; n < 4; ++n) {
        int gj = col0 + wc * 64 + n * 16 + rl;
        float val = stv[n] - acc[m][n][g];
        unsigned long long p =
            ((unsigned long long)ord_from_float(val) << 32) | (unsigned int)gj;
        if (p < bst) bst = p;
      }
      #pragma unroll
      for (int mm = 1; mm < 16; mm <<= 1) {
        unsigned long long o = shfl_xor_u64(bst, mm);
        if (o < bst) bst = o;
      }
      if (rl == 0 && grow < N) atomicMin(&packed[grow], bst);
    }
  }
}

// ---------------- reduce (with last-block final fold) ----------------
// sumbuf[0]: fixed-point (x2^20) integer sum — order-independent, so the
// completion-counter pattern stays deterministic. sumbuf[1]: block counter.
__global__ __launch_bounds__(256) void reduce_kernel(
    const unsigned long long* __restrict__ packed,
    const float* __restrict__ s_in, float* __restrict__ out,
    unsigned long long* __restrict__ sumbuf, int N, int nblocks) {
  int i = blockIdx.x * 256 + threadIdx.x;
  double local = 0.0;
  if (i < N) {
    unsigned long long p = packed[i];
    out[1 + i] = (float)(unsigned int)(p & 0xffffffffull);
    float val = float_from_ord((unsigned int)(p >> 32));
    local = (double)(s_in[i] + val);
  }
  __shared__ double sh[256];
  sh[threadIdx.x] = local;
  __syncthreads();
  for (int o = 128; o > 0; o >>= 1) {
    if (threadIdx.x < o) sh[threadIdx.x] += sh[threadIdx.x + o];
    __syncthreads();
  }
  if (threadIdx.x == 0) {
    long long q = __double2ll_rn(sh[0] * 1048576.0);
    atomicAdd(&sumbuf[0], (unsigned long long)q);
    __threadfence();  // make the add visible before signaling completion
    unsigned long long done = atomicAdd(&sumbuf[1], 1ull);
    if (done == (unsigned long long)(nblocks - 1)) {
      unsigned long long s = atomicAdd(&sumbuf[0], 0ull);  // atomic read
      out[0] = (float)(((double)(long long)s / 1048576.0) / (double)N);
    }
  }
}

extern "C" void kernel_launch(void* const* d_in, const int* in_sizes, int n_in,
                              void* d_out, int out_size, void* d_ws, size_t ws_size,
                              hipStream_t stream) {
  const float* inp = (const float*)d_in[0];
  const float* tgt = (const float*)d_in[1];
  float* out = (float*)d_out;

  int N = out_size - 1;  // outputs: [loss scalar, match[N]]
  int D = in_sizes[0] / N;
  int M = in_sizes[1] / D;

  int Npad = ((N + BT - 1) / BT) * BT;
  int Mpad = ((M + BT - 1) / BT) * BT;
  int DP = ((D + 31) / 32) * 32;  // 192 for D=180
  int gx = Mpad / BT, gy = Npad / BT;

  // Workspace layout. CRITICAL (r17 lesson): Acat/Bcat must be 256-B aligned.
  char* ws = (char*)d_ws;
  size_t off = 0;
  float* s_in = (float*)(ws + off); off += (size_t)N * 4;
  float* s_st = (float*)(ws + off); off += (size_t)M * 4;
  off = (off + 15) & ~(size_t)15;
  unsigned long long* packed = (unsigned long long*)(ws + off); off += (size_t)N * 8;
  off = (off + 15) & ~(size_t)15;
  unsigned long long* sumbuf = (unsigned long long*)(ws + off); off += 16;
  off = (off + 255) & ~(size_t)255;
  _Float16* Acat = (_Float16*)(ws + off); off += (size_t)Npad * (2 * DP) * 2;
  off = (off + 255) & ~(size_t)255;
  _Float16* Bcat = (_Float16*)(ws + off); off += (size_t)Mpad * (3 * DP) * 2;

  hipMemsetAsync(sumbuf, 0, 16, stream);  // sum + completion counter

  int pgrid = Npad > Mpad ? Npad : Mpad;
  prep_kernel<<<pgrid, 64, 0, stream>>>(inp, tgt, Acat, Bcat, s_in, s_st,
                                        packed, N, M, Npad, Mpad, D, DP);

  const int ldsBytes = 4 * UNITH * 2;  // 128 KiB
  hipFuncSetAttribute((const void*)mfma_pair_min_kernel,
                      hipFuncAttributeMaxDynamicSharedMemorySize, ldsBytes);
  mfma_pair_min_kernel<<<gx * gy, 1024, ldsBytes, stream>>>(
      Acat, Bcat, s_st, packed, N, M, DP, gx);

  int rblocks = (N + 255) / 256;
  reduce_kernel<<<rblocks, 256, 0, stream>>>(packed, s_in, out, sumbuf, N,
                                             rblocks);
}